// Round 17
// baseline (110.220 us; speedup 1.0000x reference)
//
#include <hip/hip_runtime.h>

#define N_NODES 50000
#define N_EDGES 800000
#define DIM 100

#define NB       1563       // buckets of 32 nodes
#define CAPB     768        // records per bucket (mean 512, +11 sigma)
#define OVF_CAP  4096
#define EPB      4096       // edges per bin block
#define BIN_BLOCKS  196     // ceil(800000/4096)
#define PACK_BLOCKS 306     // ceil(2,500,000 uints / 8192)
#define XB_UINTS 2500000    // 50000*50

// ---------------- workspace layout (bytes) ----------------
#define XB_OFF    0u            // uint xb[50000*50] bf16-packed x      10,000,000
#define GCUR_OFF  10000000u     // int gcur[1563]                            6,252
#define OVFC_OFF  10006272u     // int ovf_cnt (16B-aligned)                    16
#define OVF_OFF   10006288u     // int4 ovf[4096]                           65,536
#define BKT_OFF   10071824u     // uint2 bkt[1563*768]                   9,603,072
#define WTU_OFF   19674896u     // uint WtU[100*50] bf16-packed W^T         20,000
#define WS_NEED   19694896u

// float->bf16 RNE helpers
__device__ inline unsigned bf16hi(float v) {            // bf16 in HIGH 16 bits
    unsigned u = __float_as_uint(v);
    u += 0x7FFFu + ((u >> 16) & 1u);
    return u & 0xFFFF0000u;
}
__device__ inline unsigned bf16pair(float lo, float hi) {  // lo in LOW ushort
    unsigned ulo = __float_as_uint(lo); ulo += 0x7FFFu + ((ulo >> 16) & 1u);
    unsigned uhi = __float_as_uint(hi); uhi += 0x7FFFu + ((uhi >> 16) & 1u);
    return (ulo >> 16) | (uhi & 0xFFFF0000u);
}

// ---------------- fused: bin (full machine) + pack-x + WtU build ----------
// bid < 196:        bin 4096 edges -> 1563 32-node buckets (LDS hist + one
//                   gcur atomic per (block,bucket) contiguous run).
// 196 <= bid < 502: pack x (fp32 20MB) -> xb (bf16 10MB), coalesced.
// bid == 502:       WtU[k][c2] = bf16pair(W[2c2][k], W[2c2+1][k]).
__global__ __launch_bounds__(512) void srgnn_prep_bin(
    const float* __restrict__ x, const float* __restrict__ W,
    const int* __restrict__ esrc, const int* __restrict__ edst,
    const float* __restrict__ ew, unsigned* __restrict__ xb,
    unsigned* __restrict__ WtU, int* __restrict__ gcur,
    int* __restrict__ ovfc, int4* __restrict__ ovf, uint2* __restrict__ bkt)
{
    __shared__ int hist[NB];
    __shared__ int lcur[NB];
    const int t = threadIdx.x;

    if (blockIdx.x < BIN_BLOCKS) {
        // ---------------- bin ----------------
        const int e0 = blockIdx.x * EPB;

        for (int i = t; i < NB; i += 512) hist[i] = 0;
        __syncthreads();

        int d[8];
        #pragma unroll
        for (int k = 0; k < 8; ++k) {
            const int e = e0 + t + k * 512;
            d[k] = (e < N_EDGES) ? edst[e] : -1;
            if (d[k] >= 0) atomicAdd(&hist[d[k] >> 5], 1);
        }
        __syncthreads();
        for (int i = t; i < NB; i += 512)
            if (hist[i]) lcur[i] = atomicAdd(&gcur[i], hist[i]);
        __syncthreads();
        #pragma unroll
        for (int k = 0; k < 8; ++k) {
            if (d[k] >= 0) {
                const int e = e0 + t + k * 512;
                const int s = esrc[e];
                const float w = ew[e];
                const int bq = d[k] >> 5;
                const int pos = atomicAdd(&lcur[bq], 1);
                if (pos < CAPB) {
                    bkt[(size_t)bq * CAPB + pos] =
                        make_uint2((unsigned)s | bf16hi(w), (unsigned)d[k]);
                } else {
                    const int op = atomicAdd(ovfc, 1);
                    if (op < OVF_CAP) ovf[op] = make_int4(d[k], s, __float_as_int(w), 0);
                }
            }
        }
    } else if (blockIdx.x < BIN_BLOCKS + PACK_BLOCKS) {
        // ---------------- pack x -> bf16 ----------------
        const int pb = blockIdx.x - BIN_BLOCKS;
        #pragma unroll
        for (int k = 0; k < 16; ++k) {
            const unsigned i = (unsigned)pb * 8192u + t + k * 512u;
            if (i < XB_UINTS) {
                const float2 v = *reinterpret_cast<const float2*>(&x[2 * (size_t)i]);
                xb[i] = bf16pair(v.x, v.y);
            }
        }
    } else {
        // ---------------- WtU build ----------------
        for (int i = t; i < DIM * 50; i += 512) {
            const int k = i / 50, c2 = i - k * 50;
            WtU[i] = bf16pair(W[(2 * c2) * DIM + k], W[(2 * c2 + 1) * DIM + k]);
        }
    }
}

// ---------------- agg + fused GEMM epilogue -------------------------------
// Block per 32-node bucket: stage+counting-sort records; gather bf16 x-rows
// (8-deep MLP) accumulating aggrow = sum w*x[src] and sumw; write rows to
// LDS; epilogue: out[n][c] = sum_k rows[n][k]*Wt[k][c] + sumw[n]*b[c] with
// Wt bf16 LDS-resident. GEMM FLOPs hide in the gather's idle VALU slots.
__global__ __launch_bounds__(256) void srgnn_agg_gemm(
    const unsigned* __restrict__ xb, const int* __restrict__ gcur,
    const uint2* __restrict__ bkt, const int* __restrict__ ovfc,
    const int4* __restrict__ ovf, const unsigned* __restrict__ WtUg,
    const float* __restrict__ b, float* __restrict__ out)
{
    __shared__ __align__(16) unsigned WtLDS[DIM * 50];   // 20000 B
    __shared__ __align__(16) char ubuf[12800];           // recs (6144) U rows
    __shared__ unsigned srt[CAPB];                       // 3072 B
    __shared__ int nh[32], sc[32], cur[32];
    __shared__ float sums[32];

    uint2* recs = reinterpret_cast<uint2*>(ubuf);
    float (*rows)[DIM] = reinterpret_cast<float (*)[DIM]>(ubuf);

    const int t = threadIdx.x;
    const int bq = blockIdx.x;

    // stage WtU (overlaps with sort phases; consumed after barriers)
    for (int i = t; i < 1250; i += 256)
        reinterpret_cast<uint4*>(WtLDS)[i] =
            reinterpret_cast<const uint4*>(WtUg)[i];

    const int craw = gcur[bq];
    const int cntb = (craw > CAPB) ? CAPB : craw;

    if (t < 32) nh[t] = 0;
    __syncthreads();
    for (int i = t; i < cntb; i += 256) {
        const uint2 r = bkt[(size_t)bq * CAPB + i];
        recs[i] = r;
        atomicAdd(&nh[r.y & 31], 1);
    }
    __syncthreads();
    if (t < 32) sc[t] = nh[t];
    __syncthreads();
    for (int ofs = 1; ofs < 32; ofs <<= 1) {             // inclusive scan
        int a = 0;
        if (t < 32 && t >= ofs) a = sc[t - ofs];
        __syncthreads();
        if (t < 32) sc[t] += a;
        __syncthreads();
    }
    if (t < 32) cur[t] = sc[t] - nh[t];
    __syncthreads();
    for (int i = t; i < cntb; i += 256) {
        const uint2 r = recs[i];
        const int pos = atomicAdd(&cur[r.y & 31], 1);
        srt[pos] = r.x;                                  // src | bf16(w)<<16
    }
    __syncthreads();                                     // recs dead; rows alive

    int oc = *ovfc;                                      // ~always 0
    if (oc > OVF_CAP) oc = OVF_CAP;
    const int lane = t & 63;
    const int wid  = t >> 6;                             // 4 waves
    const bool active = (lane < 50);

    for (int q = 0; q < 8; ++q) {
        const int n  = wid * 8 + q;                      // 4 waves x 8 = 32
        const int s1 = sc[n];
        const int s0 = s1 - nh[n];
        float2 acc = make_float2(0.f, 0.f);
        float sumw = 0.f;

        int p = s0;
        for (; p + 8 <= s1; p += 8) {                    // 8-deep MLP
            unsigned r[8], h[8];
            #pragma unroll
            for (int j = 0; j < 8; ++j) r[j] = srt[p + j];
            #pragma unroll
            for (int j = 0; j < 8; ++j)
                sumw += __uint_as_float(r[j] & 0xFFFF0000u);
            if (active) {
                #pragma unroll
                for (int j = 0; j < 8; ++j)
                    h[j] = xb[(size_t)(r[j] & 0xFFFFu) * 50 + lane];
                #pragma unroll
                for (int j = 0; j < 8; ++j) {
                    const float wj = __uint_as_float(r[j] & 0xFFFF0000u);
                    acc.x += wj * __uint_as_float(h[j] << 16);
                    acc.y += wj * __uint_as_float(h[j] & 0xFFFF0000u);
                }
            }
        }
        for (; p < s1; ++p) {
            const unsigned r = srt[p];
            const float wi = __uint_as_float(r & 0xFFFF0000u);
            sumw += wi;
            if (active) {
                const unsigned h = xb[(size_t)(r & 0xFFFFu) * 50 + lane];
                acc.x += wi * __uint_as_float(h << 16);
                acc.y += wi * __uint_as_float(h & 0xFFFF0000u);
            }
        }

        const int ng = bq * 32 + n;
        if (craw > CAPB && oc > 0) {                     // ultra-rare overflow
            for (int i = 0; i < oc; ++i) {
                const int4 v = ovf[i];
                if (v.x == ng) {
                    const float wi = __int_as_float(v.z);
                    sumw += wi;
                    if (active) {
                        const unsigned h = xb[(size_t)v.y * 50 + lane];
                        acc.x += wi * __uint_as_float(h << 16);
                        acc.y += wi * __uint_as_float(h & 0xFFFF0000u);
                    }
                }
            }
        }
        if (active) {
            rows[n][2 * lane]     = acc.x;
            rows[n][2 * lane + 1] = acc.y;
        }
        if (lane == 0) sums[n] = sumw;
    }
    __syncthreads();

    // epilogue GEMM: out[n][c] = sum_k rows[n][k]*Wt[k][c] + sums[n]*b[c]
    {
        const int n = t >> 3;                            // 0..31
        const int q = t & 7;
        const int ng = bq * 32 + n;
        if (ng < N_NODES) {
            const float sw = sums[n];
            for (int c2 = q; c2 < 50; c2 += 8) {
                const float2 bv = *reinterpret_cast<const float2*>(&b[2 * c2]);
                float ax = sw * bv.x;
                float ay = sw * bv.y;
                #pragma unroll 4
                for (int k = 0; k < DIM; ++k) {
                    const float rk = rows[n][k];
                    const unsigned u = WtLDS[k * 50 + c2];
                    ax += rk * __uint_as_float(u << 16);
                    ay += rk * __uint_as_float(u & 0xFFFF0000u);
                }
                *reinterpret_cast<float2*>(&out[(size_t)ng * DIM + 2 * c2]) =
                    make_float2(ax, ay);
            }
        }
    }
}

// ---------------- fallback (atomic scatter, needs only 20MB ws) ----------
__global__ __launch_bounds__(256) void srgnn_gemm_bias(
    const float* __restrict__ x, const float* __restrict__ W,
    const float* __restrict__ b, float* __restrict__ hidden)
{
    __shared__ float Wt[DIM][DIM + 4];
    __shared__ float bs[DIM];
    __shared__ float xs[8][DIM];
    const int t = threadIdx.x;
    for (int i = t; i < DIM * DIM; i += 256) {
        int c = i / DIM, k = i - c * DIM;
        Wt[k][c] = W[i];
    }
    if (t < DIM) bs[t] = b[t];
    const int row0 = blockIdx.x * 8;
    for (int i = t; i < 8 * DIM; i += 256) {
        int r = i / DIM, k = i - r * DIM;
        int row = row0 + r;
        xs[r][k] = (row < N_NODES) ? x[row * DIM + k] : 0.0f;
    }
    __syncthreads();
    if (t < 200) {
        const int r  = t / 25;
        const int c4 = (t - r * 25) * 4;
        float acc0 = bs[c4 + 0], acc1 = bs[c4 + 1], acc2 = bs[c4 + 2], acc3 = bs[c4 + 3];
        for (int k = 0; k < DIM; ++k) {
            const float xv = xs[r][k];
            const float4 wv = *reinterpret_cast<const float4*>(&Wt[k][c4]);
            acc0 += xv * wv.x; acc1 += xv * wv.y; acc2 += xv * wv.z; acc3 += xv * wv.w;
        }
        const int row = row0 + r;
        if (row < N_NODES)
            *reinterpret_cast<float4*>(&hidden[row * DIM + c4]) =
                make_float4(acc0, acc1, acc2, acc3);
    }
}

__global__ __launch_bounds__(256) void srgnn_scatter_atomic(
    const float* __restrict__ hidden, const int* __restrict__ esrc,
    const int* __restrict__ edst, const float* __restrict__ ew,
    float* __restrict__ out)
{
    const unsigned gid = blockIdx.x * 256u + threadIdx.x;
    const unsigned e = gid / 25u;
    const unsigned j = gid - e * 25u;
    if (e >= N_EDGES) return;
    const int   s  = esrc[e];
    const int   d  = edst[e];
    const float wt = ew[e];
    const float4 h = *reinterpret_cast<const float4*>(&hidden[(size_t)s * DIM + j * 4]);
    float* op = &out[(size_t)d * DIM + j * 4];
    atomicAdd(op + 0, h.x * wt);
    atomicAdd(op + 1, h.y * wt);
    atomicAdd(op + 2, h.z * wt);
    atomicAdd(op + 3, h.w * wt);
}

extern "C" void kernel_launch(void* const* d_in, const int* in_sizes, int n_in,
                              void* d_out, int out_size, void* d_ws, size_t ws_size,
                              hipStream_t stream) {
    const float* x    = (const float*)d_in[0];
    const int*   esrc = (const int*)  d_in[1];
    const int*   edst = (const int*)  d_in[2];
    const float* ew   = (const float*)d_in[3];
    const float* W    = (const float*)d_in[4];
    const float* b    = (const float*)d_in[5];
    float* out = (float*)d_out;

    char* ws = (char*)d_ws;

    if (ws_size >= WS_NEED) {
        unsigned* xb   = (unsigned*)(ws + XB_OFF);
        int*      gcur = (int*)     (ws + GCUR_OFF);
        int*      ovfc = (int*)     (ws + OVFC_OFF);
        int4*     ovf  = (int4*)    (ws + OVF_OFF);
        uint2*    bkt  = (uint2*)   (ws + BKT_OFF);
        unsigned* WtU  = (unsigned*)(ws + WTU_OFF);

        // zero bucket cursors + overflow counter (contiguous region)
        hipMemsetAsync(gcur, 0, (OVFC_OFF - GCUR_OFF) + 16, stream);
        // fused: bin (196 blocks, full machine) + pack-x (306) + WtU (1)
        srgnn_prep_bin<<<BIN_BLOCKS + PACK_BLOCKS + 1, 512, 0, stream>>>(
            x, W, esrc, edst, ew, xb, WtU, gcur, ovfc, ovf, bkt);
        // aggregate in x-space + fused GEMM epilogue
        srgnn_agg_gemm<<<NB, 256, 0, stream>>>(
            xb, gcur, bkt, ovfc, ovf, WtU, b, out);
    } else {
        // fallback: atomic scatter
        float* hidden = (float*)ws;
        hipMemsetAsync(d_out, 0, (size_t)out_size * sizeof(float), stream);
        const int gemm_blocks = (N_NODES + 7) / 8;
        srgnn_gemm_bias<<<gemm_blocks, 256, 0, stream>>>(x, W, b, hidden);
        const long long work = (long long)N_EDGES * 25;
        const int scat_blocks = (int)((work + 255) / 256);
        srgnn_scatter_atomic<<<scat_blocks, 256, 0, stream>>>(hidden, esrc, edst, ew, out);
    }
}

// Round 18
// 73.658 us; speedup vs baseline: 1.4964x; 1.4964x over previous
//
#include <hip/hip_runtime.h>

#define N_NODES 50000
#define N_EDGES 800000
#define DIM 100

#define NB      1563        // buckets of 32 nodes: ceil(50000/32)
#define CAPB    768         // records per bucket region (mean 512, +11 sigma)
#define OVF_CAP 4096
#define EPB     8192        // edges per bin block
#define BIN_BLOCKS  98      // ceil(800000 / 8192)
#define GEMM_BLOCKS 625     // 50000 / 80
#define ROWS_PB 80          // gemm rows per (512-thread) block

// ---------------- workspace layout (bytes) ----------------
#define HIDB_OFF  0u            // bf16 hidden, packed uint[50000*50]   10,000,000
#define GCUR_OFF  10000000u     // int gcur[1563]                            6,256
#define OVFC_OFF  10006256u     // int ovf_cnt (+pad)                           16
#define OVF_OFF   10006272u     // int4 ovf[4096]                           65,536
#define BKT2_OFF  10071808u     // uint2 bkt2[1563*768] (128B-aligned)   9,603,072
#define WT_OFF    19674880u     // float Wt[100*100]                        40,000
#define WS_NEED   19714880u

// float->bf16 RNE helpers
__device__ inline unsigned bf16hi(float v) {            // bf16 in HIGH 16 bits
    unsigned u = __float_as_uint(v);
    u += 0x7FFFu + ((u >> 16) & 1u);
    return u & 0xFFFF0000u;
}
__device__ inline unsigned bf16pair(float lo, float hi) {
    unsigned ulo = __float_as_uint(lo); ulo += 0x7FFFu + ((ulo >> 16) & 1u);
    unsigned uhi = __float_as_uint(hi); uhi += 0x7FFFu + ((uhi >> 16) & 1u);
    return (ulo >> 16) | (uhi & 0xFFFF0000u);
}

// ---------------- transpose + control-buffer zeroing ----------------
__global__ __launch_bounds__(256) void srgnn_transpose(
    const float* __restrict__ W, float* __restrict__ Wt,
    int* __restrict__ gcur, int* __restrict__ ovfc)
{
    const unsigned i = blockIdx.x * 256u + threadIdx.x;
    if (i < DIM * DIM) {
        const int c = i / DIM, k = i - c * DIM;
        Wt[k * DIM + c] = W[i];
    }
    if (i < NB) gcur[i] = 0;
    if (i == 0) *ovfc = 0;
}

// ---------------- fused bin + GEMM (bin FIRST: bid<98) --------------------
// bin role: single-pass bucket scatter (8192 edges -> 1563 32-node buckets
// via LDS hist + one gcur atomic per (block,bucket) contiguous run).
// gemm role: hidden(bf16) = x @ W^T + b, xs in LDS (32KB -> 4 blocks/CU,
// 32 waves), Wt from GLOBAL but with the k-loop SPLIT IN HALVES so the
// active Wt working set is 20KB <= 32KB L1 and shared by all co-resident
// blocks (same addresses). R9's unsplit version (40KB > L1) thrashed ->
// VALUBusy 27%; R15's LDS-Wt version paid 72KB LDS (2 blocks/CU) + 1.69M
// bank conflicts. This keeps full occupancy AND L1-resident Wt.
__global__ __launch_bounds__(512) void srgnn_gemm_bin(
    const float* __restrict__ x, const float* __restrict__ Wtg,
    const float* __restrict__ b, unsigned* __restrict__ hidU,
    const int* __restrict__ esrc, const int* __restrict__ edst,
    const float* __restrict__ ew, int* __restrict__ gcur,
    int* __restrict__ ovfc, int4* __restrict__ ovf, uint2* __restrict__ bkt2)
{
    __shared__ __align__(16) char smem[32000];
    const int t = threadIdx.x;

    if (blockIdx.x < BIN_BLOCKS) {
        // ---------------- bin part ----------------
        int* hist = (int*)smem;                      // NB ints
        int* lcur = hist + NB;                       // NB ints (12504 B)
        const int e0 = blockIdx.x * EPB;

        for (int i = t; i < NB; i += 512) hist[i] = 0;
        __syncthreads();

        int d[16];
        #pragma unroll
        for (int k = 0; k < 16; ++k) {
            const int e = e0 + t + k * 512;
            d[k] = (e < N_EDGES) ? edst[e] : -1;
            if (d[k] >= 0) atomicAdd(&hist[d[k] >> 5], 1);
        }
        __syncthreads();
        for (int i = t; i < NB; i += 512)
            if (hist[i]) lcur[i] = atomicAdd(&gcur[i], hist[i]);
        __syncthreads();
        #pragma unroll
        for (int k = 0; k < 16; ++k) {
            if (d[k] >= 0) {
                const int e = e0 + t + k * 512;
                const int s = esrc[e];
                const float w = ew[e];
                const int bq = d[k] >> 5;
                const int pos = atomicAdd(&lcur[bq], 1);
                if (pos < CAPB) {
                    bkt2[(size_t)bq * CAPB + pos] =
                        make_uint2((unsigned)s | bf16hi(w), (unsigned)d[k]);
                } else {
                    const int op = atomicAdd(ovfc, 1);
                    if (op < OVF_CAP) ovf[op] = make_int4(d[k], s, __float_as_int(w), 0);
                }
            }
        }
    } else {
        // ---------------- GEMM part ----------------
        float (*xs)[DIM] = (float (*)[DIM])smem;     // 80x100 floats = 32000 B
        const int row0 = (blockIdx.x - BIN_BLOCKS) * ROWS_PB;

        for (int i = t; i < ROWS_PB * 25; i += 512) {
            const int r = i / 25, c4 = (i - r * 25) * 4;
            const float4 v = *reinterpret_cast<const float4*>(
                &x[(size_t)(row0 + r) * DIM + c4]);
            *reinterpret_cast<float4*>(&xs[r][c4]) = v;
        }
        __syncthreads();

        if (t < 500) {
            const int g  = t / 25;            // row group 0..19
            const int c4 = (t - g * 25) * 4;  // col chunk
            const float4 bv = *reinterpret_cast<const float4*>(&b[c4]);
            float4 a0 = bv, a1 = bv, a2 = bv, a3 = bv;

            // k split in halves: active Wt working set = 20KB (L1-resident,
            // shared across co-resident blocks reading identical addresses)
            #pragma unroll
            for (int kh = 0; kh < 2; ++kh) {
                const int kbase = kh * 50;
                #pragma unroll 5
                for (int kk = 0; kk < 50; ++kk) {
                    const int k = kbase + kk;
                    const float4 wv = *reinterpret_cast<const float4*>(
                        &Wtg[k * DIM + c4]);
                    const float x0 = xs[g     ][k];
                    const float x1 = xs[g + 20][k];
                    const float x2 = xs[g + 40][k];
                    const float x3 = xs[g + 60][k];
                    a0.x += x0 * wv.x; a0.y += x0 * wv.y; a0.z += x0 * wv.z; a0.w += x0 * wv.w;
                    a1.x += x1 * wv.x; a1.y += x1 * wv.y; a1.z += x1 * wv.z; a1.w += x1 * wv.w;
                    a2.x += x2 * wv.x; a2.y += x2 * wv.y; a2.z += x2 * wv.z; a2.w += x2 * wv.w;
                    a3.x += x3 * wv.x; a3.y += x3 * wv.y; a3.z += x3 * wv.z; a3.w += x3 * wv.w;
                }
            }
            const int u0 = c4 >> 1;           // uint index within row
            uint2 p;
            p.x = bf16pair(a0.x, a0.y); p.y = bf16pair(a0.z, a0.w);
            *reinterpret_cast<uint2*>(&hidU[(size_t)(row0 + g     ) * 50 + u0]) = p;
            p.x = bf16pair(a1.x, a1.y); p.y = bf16pair(a1.z, a1.w);
            *reinterpret_cast<uint2*>(&hidU[(size_t)(row0 + g + 20) * 50 + u0]) = p;
            p.x = bf16pair(a2.x, a2.y); p.y = bf16pair(a2.z, a2.w);
            *reinterpret_cast<uint2*>(&hidU[(size_t)(row0 + g + 40) * 50 + u0]) = p;
            p.x = bf16pair(a3.x, a3.y); p.y = bf16pair(a3.z, a3.w);
            *reinterpret_cast<uint2*>(&hidU[(size_t)(row0 + g + 60) * 50 + u0]) = p;
        }
    }
}

// ---------------- aggregate: block per 32-node bucket, LDS counting sort --
__global__ __launch_bounds__(256) void srgnn_agg_s32(
    const unsigned* __restrict__ hidU, const int* __restrict__ gcur,
    const uint2* __restrict__ bkt2, const int* __restrict__ ovfc,
    const int4* __restrict__ ovf, float* __restrict__ out)
{
    __shared__ uint2    recs[CAPB];     // 6144 B
    __shared__ unsigned srt[CAPB];      // 3072 B
    __shared__ int nh[32], sc[32], cur[32];

    const int t = threadIdx.x;
    const int bq = blockIdx.x;
    int cntb = gcur[bq];
    if (cntb > CAPB) cntb = CAPB;

    if (t < 32) nh[t] = 0;
    __syncthreads();
    for (int i = t; i < cntb; i += 256) {
        const uint2 r = bkt2[(size_t)bq * CAPB + i];
        recs[i] = r;
        atomicAdd(&nh[r.y & 31], 1);
    }
    __syncthreads();
    if (t < 32) sc[t] = nh[t];
    __syncthreads();
    for (int ofs = 1; ofs < 32; ofs <<= 1) {         // Hillis-Steele inclusive
        int a = 0;
        if (t < 32 && t >= ofs) a = sc[t - ofs];
        __syncthreads();
        if (t < 32) sc[t] += a;
        __syncthreads();
    }
    if (t < 32) cur[t] = sc[t] - nh[t];
    __syncthreads();
    for (int i = t; i < cntb; i += 256) {
        const uint2 r = recs[i];
        const int pos = atomicAdd(&cur[r.y & 31], 1);
        srt[pos] = r.x;                              // src | bf16(w)<<16
    }
    __syncthreads();

    int oc = *ovfc;                                  // ~always 0
    if (oc > OVF_CAP) oc = OVF_CAP;
    const int lane = t & 63;
    const int wid  = t >> 6;                         // 4 waves
    const bool active = (lane < 50);

    for (int q = 0; q < 8; ++q) {
        const int n  = wid * 8 + q;                  // 4 waves x 8 = 32 nodes
        const int s1 = sc[n];
        const int s0 = s1 - nh[n];
        float2 acc = make_float2(0.f, 0.f);

        int p = s0;
        for (; p + 8 <= s1; p += 8) {                // 8-deep MLP
            unsigned r[8], h[8];
            #pragma unroll
            for (int j = 0; j < 8; ++j) r[j] = srt[p + j];
            if (active) {
                #pragma unroll
                for (int j = 0; j < 8; ++j)
                    h[j] = hidU[(size_t)(r[j] & 0xFFFFu) * 50 + lane];
                #pragma unroll
                for (int j = 0; j < 8; ++j) {
                    const float wj = __uint_as_float(r[j] & 0xFFFF0000u);
                    acc.x += wj * __uint_as_float(h[j] << 16);
                    acc.y += wj * __uint_as_float(h[j] & 0xFFFF0000u);
                }
            }
        }
        for (; p < s1; ++p) {
            const unsigned r = srt[p];
            const float wi = __uint_as_float(r & 0xFFFF0000u);
            if (active) {
                const unsigned h = hidU[(size_t)(r & 0xFFFFu) * 50 + lane];
                acc.x += wi * __uint_as_float(h << 16);
                acc.y += wi * __uint_as_float(h & 0xFFFF0000u);
            }
        }

        const int ng = bq * 32 + n;
        if (oc > 0) {                                // ultra-rare overflow scan
            for (int i = 0; i < oc; ++i) {
                const int4 v = ovf[i];
                if (v.x == ng && active) {
                    const unsigned h = hidU[(size_t)v.y * 50 + lane];
                    const float wi = __int_as_float(v.z);
                    acc.x += wi * __uint_as_float(h << 16);
                    acc.y += wi * __uint_as_float(h & 0xFFFF0000u);
                }
            }
        }
        if (ng < N_NODES && active)
            *reinterpret_cast<float2*>(&out[(size_t)ng * DIM + 2 * lane]) = acc;
    }
}

// ---------------- fallback (atomic scatter, needs only 20MB ws) ----------
__global__ __launch_bounds__(256) void srgnn_gemm_bias(
    const float* __restrict__ x, const float* __restrict__ W,
    const float* __restrict__ b, float* __restrict__ hidden)
{
    __shared__ float Wt[DIM][DIM + 4];
    __shared__ float bs[DIM];
    __shared__ float xs[8][DIM];
    const int t = threadIdx.x;
    for (int i = t; i < DIM * DIM; i += 256) {
        int c = i / DIM, k = i - c * DIM;
        Wt[k][c] = W[i];
    }
    if (t < DIM) bs[t] = b[t];
    const int row0 = blockIdx.x * 8;
    for (int i = t; i < 8 * DIM; i += 256) {
        int r = i / DIM, k = i - r * DIM;
        int row = row0 + r;
        xs[r][k] = (row < N_NODES) ? x[row * DIM + k] : 0.0f;
    }
    __syncthreads();
    if (t < 200) {
        const int r  = t / 25;
        const int c4 = (t - r * 25) * 4;
        float acc0 = bs[c4 + 0], acc1 = bs[c4 + 1], acc2 = bs[c4 + 2], acc3 = bs[c4 + 3];
        for (int k = 0; k < DIM; ++k) {
            const float xv = xs[r][k];
            const float4 wv = *reinterpret_cast<const float4*>(&Wt[k][c4]);
            acc0 += xv * wv.x; acc1 += xv * wv.y; acc2 += xv * wv.z; acc3 += xv * wv.w;
        }
        const int row = row0 + r;
        if (row < N_NODES)
            *reinterpret_cast<float4*>(&hidden[row * DIM + c4]) =
                make_float4(acc0, acc1, acc2, acc3);
    }
}

__global__ __launch_bounds__(256) void srgnn_scatter_atomic(
    const float* __restrict__ hidden, const int* __restrict__ esrc,
    const int* __restrict__ edst, const float* __restrict__ ew,
    float* __restrict__ out)
{
    const unsigned gid = blockIdx.x * 256u + threadIdx.x;
    const unsigned e = gid / 25u;
    const unsigned j = gid - e * 25u;
    if (e >= N_EDGES) return;
    const int   s  = esrc[e];
    const int   d  = edst[e];
    const float wt = ew[e];
    const float4 h = *reinterpret_cast<const float4*>(&hidden[(size_t)s * DIM + j * 4]);
    float* op = &out[(size_t)d * DIM + j * 4];
    atomicAdd(op + 0, h.x * wt);
    atomicAdd(op + 1, h.y * wt);
    atomicAdd(op + 2, h.z * wt);
    atomicAdd(op + 3, h.w * wt);
}

extern "C" void kernel_launch(void* const* d_in, const int* in_sizes, int n_in,
                              void* d_out, int out_size, void* d_ws, size_t ws_size,
                              hipStream_t stream) {
    const float* x    = (const float*)d_in[0];
    const int*   esrc = (const int*)  d_in[1];
    const int*   edst = (const int*)  d_in[2];
    const float* ew   = (const float*)d_in[3];
    const float* W    = (const float*)d_in[4];
    const float* b    = (const float*)d_in[5];
    float* out = (float*)d_out;

    char* ws = (char*)d_ws;

    if (ws_size >= WS_NEED) {
        unsigned* hidU = (unsigned*)(ws + HIDB_OFF);
        int*      gcur = (int*)     (ws + GCUR_OFF);
        int*      ovfc = (int*)     (ws + OVFC_OFF);
        int4*     ovf  = (int4*)    (ws + OVF_OFF);
        uint2*    bkt2 = (uint2*)   (ws + BKT2_OFF);
        float*    Wt   = (float*)   (ws + WT_OFF);

        // transpose W + zero control buffers (one dispatch)
        srgnn_transpose<<<(DIM * DIM + 255) / 256, 256, 0, stream>>>(W, Wt, gcur, ovfc);
        // fused: bin (98 blocks, FIRST) + GEMM w/ k-split L1-resident Wt
        srgnn_gemm_bin<<<BIN_BLOCKS + GEMM_BLOCKS, 512, 0, stream>>>(
            x, Wt, b, hidU, esrc, edst, ew, gcur, ovfc, ovf, bkt2);
        // block-per-bucket LDS sort + aggregate
        srgnn_agg_s32<<<NB, 256, 0, stream>>>(hidU, gcur, bkt2, ovfc, ovf, out);
    } else {
        // fallback: atomic scatter
        float* hidden = (float*)ws;
        hipMemsetAsync(d_out, 0, (size_t)out_size * sizeof(float), stream);
        const int gemm_blocks = (N_NODES + 7) / 8;
        srgnn_gemm_bias<<<gemm_blocks, 256, 0, stream>>>(x, W, b, hidden);
        const long long work = (long long)N_EDGES * 25;
        const int scat_blocks = (int)((work + 255) / 256);
        srgnn_scatter_atomic<<<scat_blocks, 256, 0, stream>>>(hidden, esrc, edst, ew, out);
    }
}

// Round 20
// 70.415 us; speedup vs baseline: 1.5653x; 1.0461x over previous
//
#include <hip/hip_runtime.h>

#define N_NODES 50000
#define N_EDGES 800000
#define DIM 100

#define NB      1563        // buckets of 32 nodes: ceil(50000/32)
#define CAPB    768         // records per bucket region (mean 512, +11 sigma)
#define OVF_CAP 4096
#define EPB     4096        // edges per bin block
#define BIN_BLOCKS  196     // ceil(800000 / 4096)
#define GEMM_BLOCKS 625     // 50000 / 80
#define ROWS_PB 80          // gemm rows per block

// ---------------- workspace layout (bytes) ----------------
#define HIDB_OFF  0u            // bf16 hidden, packed uint[50000*50]   10,000,000
#define GCUR_OFF  10000000u     // int gcur[1563]                            6,256
#define OVFC_OFF  10006256u     // int ovf_cnt (+pad)                           16
#define OVF_OFF   10006272u     // int4 ovf[4096]                           65,536
#define BKT2_OFF  10071808u     // uint2 bkt2[1563*768] (128B-aligned)   9,603,072
#define WTU_OFF   19674880u     // uint WtU[100*50] bf16-packed W^T         20,000
#define WS_NEED   19694880u

// float->bf16 RNE helpers
__device__ inline unsigned bf16hi(float v) {            // bf16 in HIGH 16 bits
    unsigned u = __float_as_uint(v);
    u += 0x7FFFu + ((u >> 16) & 1u);
    return u & 0xFFFF0000u;
}
__device__ inline unsigned bf16pair(float lo, float hi) {  // lo in LOW ushort
    unsigned ulo = __float_as_uint(lo); ulo += 0x7FFFu + ((ulo >> 16) & 1u);
    unsigned uhi = __float_as_uint(hi); uhi += 0x7FFFu + ((uhi >> 16) & 1u);
    return (ulo >> 16) | (uhi & 0xFFFF0000u);
}
#define BFLO(u) __uint_as_float((u) << 16)
#define BFHI(u) __uint_as_float((u) & 0xFFFF0000u)

// ---------------- transpose->bf16 + control-buffer zeroing ----------------
// WtU[k*50+c2] = bf16pair(W[2c2][k], W[2c2+1][k])  (20KB, fits L1 whole)
// Grid must cover DIM*50 = 5000 threads (R19 bug: only 1792 launched).
__global__ __launch_bounds__(256) void srgnn_transpose(
    const float* __restrict__ W, unsigned* __restrict__ WtU,
    int* __restrict__ gcur, int* __restrict__ ovfc)
{
    const unsigned i = blockIdx.x * 256u + threadIdx.x;
    if (i < DIM * 50) {
        const int k = i / 50, c2 = i - k * 50;
        WtU[i] = bf16pair(W[(2 * c2) * DIM + k], W[(2 * c2 + 1) * DIM + k]);
    }
    if (i < NB) gcur[i] = 0;
    if (i == 0) *ovfc = 0;
}

// ---------------- fused bin + GEMM (bin FIRST: bid<196) -------------------
// bin role: single-pass bucket scatter, 4096 edges/block.
// gemm role: hidden(bf16) = x @ W^T + b. Byte/FMA balance: 8 rows x 4 cols
// per thread, k-unroll 4 -> per 4k: 8 xs float4 (LDS broadcast) + 4 Wt
// uint2 (bf16, 20KB L1-resident whole) + 128 FMA = 1.0 B/FMA LDS,
// 0.25 B/FMA L1. Previous variants read 2 B/FMA -> operand-bound at
// VALUBusy ~30% regardless of Wt location.
__global__ __launch_bounds__(256) void srgnn_gemm_bin(
    const float* __restrict__ x, const unsigned* __restrict__ WtU,
    const float* __restrict__ b, unsigned* __restrict__ hidU,
    const int* __restrict__ esrc, const int* __restrict__ edst,
    const float* __restrict__ ew, int* __restrict__ gcur,
    int* __restrict__ ovfc, int4* __restrict__ ovf, uint2* __restrict__ bkt2)
{
    __shared__ __align__(16) char smem[32000];
    const int t = threadIdx.x;

    if (blockIdx.x < BIN_BLOCKS) {
        // ---------------- bin part ----------------
        int* hist = (int*)smem;                      // NB ints
        int* lcur = hist + NB;                       // NB ints (12504 B)
        const int e0 = blockIdx.x * EPB;

        for (int i = t; i < NB; i += 256) hist[i] = 0;
        __syncthreads();

        int d[16];
        #pragma unroll
        for (int k = 0; k < 16; ++k) {
            const int e = e0 + t + k * 256;
            d[k] = (e < N_EDGES) ? edst[e] : -1;
            if (d[k] >= 0) atomicAdd(&hist[d[k] >> 5], 1);
        }
        __syncthreads();
        for (int i = t; i < NB; i += 256)
            if (hist[i]) lcur[i] = atomicAdd(&gcur[i], hist[i]);
        __syncthreads();
        #pragma unroll
        for (int k = 0; k < 16; ++k) {
            if (d[k] >= 0) {
                const int e = e0 + t + k * 256;
                const int s = esrc[e];
                const float w = ew[e];
                const int bq = d[k] >> 5;
                const int pos = atomicAdd(&lcur[bq], 1);
                if (pos < CAPB) {
                    bkt2[(size_t)bq * CAPB + pos] =
                        make_uint2((unsigned)s | bf16hi(w), (unsigned)d[k]);
                } else {
                    const int op = atomicAdd(ovfc, 1);
                    if (op < OVF_CAP) ovf[op] = make_int4(d[k], s, __float_as_int(w), 0);
                }
            }
        }
    } else {
        // ---------------- GEMM part ----------------
        float (*xs)[DIM] = (float (*)[DIM])smem;     // 80x100 floats = 32000 B
        const int row0 = (blockIdx.x - BIN_BLOCKS) * ROWS_PB;

        for (int i = t; i < ROWS_PB * 25; i += 256) {
            const int r = i / 25, c4 = (i - r * 25) * 4;
            const float4 v = *reinterpret_cast<const float4*>(
                &x[(size_t)(row0 + r) * DIM + c4]);
            *reinterpret_cast<float4*>(&xs[r][c4]) = v;
        }
        __syncthreads();

        if (t < 250) {
            const int g    = t / 25;          // row group 0..9 (8 rows each)
            const int c    = t - g * 25;      // col chunk 0..24
            const int c4   = c * 4;
            const int c2ix = c * 2;           // uint index into WtU rows

            const float4 bv = *reinterpret_cast<const float4*>(&b[c4]);
            float4 acc[8];
            #pragma unroll
            for (int j = 0; j < 8; ++j) acc[j] = bv;

            for (int kq = 0; kq < 25; ++kq) {
                const int k0 = 4 * kq;
                // 4 k-rows of bf16 Wt: 4 cols each (uint2 = 8B)
                const uint2 wu0 = *reinterpret_cast<const uint2*>(&WtU[(k0 + 0) * 50 + c2ix]);
                const uint2 wu1 = *reinterpret_cast<const uint2*>(&WtU[(k0 + 1) * 50 + c2ix]);
                const uint2 wu2 = *reinterpret_cast<const uint2*>(&WtU[(k0 + 2) * 50 + c2ix]);
                const uint2 wu3 = *reinterpret_cast<const uint2*>(&WtU[(k0 + 3) * 50 + c2ix]);
                const float w00 = BFLO(wu0.x), w01 = BFHI(wu0.x), w02 = BFLO(wu0.y), w03 = BFHI(wu0.y);
                const float w10 = BFLO(wu1.x), w11 = BFHI(wu1.x), w12 = BFLO(wu1.y), w13 = BFHI(wu1.y);
                const float w20 = BFLO(wu2.x), w21 = BFHI(wu2.x), w22 = BFLO(wu2.y), w23 = BFHI(wu2.y);
                const float w30 = BFLO(wu3.x), w31 = BFHI(wu3.x), w32 = BFLO(wu3.y), w33 = BFHI(wu3.y);

                #pragma unroll
                for (int j = 0; j < 8; ++j) {
                    const float4 xv = *reinterpret_cast<const float4*>(
                        &xs[g + 10 * j][k0]);
                    acc[j].x += xv.x * w00; acc[j].y += xv.x * w01;
                    acc[j].z += xv.x * w02; acc[j].w += xv.x * w03;
                    acc[j].x += xv.y * w10; acc[j].y += xv.y * w11;
                    acc[j].z += xv.y * w12; acc[j].w += xv.y * w13;
                    acc[j].x += xv.z * w20; acc[j].y += xv.z * w21;
                    acc[j].z += xv.z * w22; acc[j].w += xv.z * w23;
                    acc[j].x += xv.w * w30; acc[j].y += xv.w * w31;
                    acc[j].z += xv.w * w32; acc[j].w += xv.w * w33;
                }
            }
            #pragma unroll
            for (int j = 0; j < 8; ++j) {
                const int row = row0 + g + 10 * j;
                uint2 p;
                p.x = bf16pair(acc[j].x, acc[j].y);
                p.y = bf16pair(acc[j].z, acc[j].w);
                *reinterpret_cast<uint2*>(&hidU[(size_t)row * 50 + c2ix]) = p;
            }
        }
    }
}

// ---------------- aggregate: block per 32-node bucket, LDS counting sort --
__global__ __launch_bounds__(256) void srgnn_agg_s32(
    const unsigned* __restrict__ hidU, const int* __restrict__ gcur,
    const uint2* __restrict__ bkt2, const int* __restrict__ ovfc,
    const int4* __restrict__ ovf, float* __restrict__ out)
{
    __shared__ uint2    recs[CAPB];     // 6144 B
    __shared__ unsigned srt[CAPB];      // 3072 B
    __shared__ int nh[32], sc[32], cur[32];

    const int t = threadIdx.x;
    const int bq = blockIdx.x;
    int cntb = gcur[bq];
    if (cntb > CAPB) cntb = CAPB;

    if (t < 32) nh[t] = 0;
    __syncthreads();
    for (int i = t; i < cntb; i += 256) {
        const uint2 r = bkt2[(size_t)bq * CAPB + i];
        recs[i] = r;
        atomicAdd(&nh[r.y & 31], 1);
    }
    __syncthreads();
    if (t < 32) sc[t] = nh[t];
    __syncthreads();
    for (int ofs = 1; ofs < 32; ofs <<= 1) {         // Hillis-Steele inclusive
        int a = 0;
        if (t < 32 && t >= ofs) a = sc[t - ofs];
        __syncthreads();
        if (t < 32) sc[t] += a;
        __syncthreads();
    }
    if (t < 32) cur[t] = sc[t] - nh[t];
    __syncthreads();
    for (int i = t; i < cntb; i += 256) {
        const uint2 r = recs[i];
        const int pos = atomicAdd(&cur[r.y & 31], 1);
        srt[pos] = r.x;                              // src | bf16(w)<<16
    }
    __syncthreads();

    int oc = *ovfc;                                  // ~always 0
    if (oc > OVF_CAP) oc = OVF_CAP;
    const int lane = t & 63;
    const int wid  = t >> 6;                         // 4 waves
    const bool active = (lane < 50);

    for (int q = 0; q < 8; ++q) {
        const int n  = wid * 8 + q;                  // 4 waves x 8 = 32 nodes
        const int s1 = sc[n];
        const int s0 = s1 - nh[n];
        float2 acc = make_float2(0.f, 0.f);

        int p = s0;
        for (; p + 8 <= s1; p += 8) {                // 8-deep MLP
            unsigned r[8], h[8];
            #pragma unroll
            for (int j = 0; j < 8; ++j) r[j] = srt[p + j];
            if (active) {
                #pragma unroll
                for (int j = 0; j < 8; ++j)
                    h[j] = hidU[(size_t)(r[j] & 0xFFFFu) * 50 + lane];
                #pragma unroll
                for (int j = 0; j < 8; ++j) {
                    const float wj = __uint_as_float(r[j] & 0xFFFF0000u);
                    acc.x += wj * __uint_as_float(h[j] << 16);
                    acc.y += wj * __uint_as_float(h[j] & 0xFFFF0000u);
                }
            }
        }
        for (; p < s1; ++p) {
            const unsigned r = srt[p];
            const float wi = __uint_as_float(r & 0xFFFF0000u);
            if (active) {
                const unsigned h = hidU[(size_t)(r & 0xFFFFu) * 50 + lane];
                acc.x += wi * __uint_as_float(h << 16);
                acc.y += wi * __uint_as_float(h & 0xFFFF0000u);
            }
        }

        const int ng = bq * 32 + n;
        if (oc > 0) {                                // ultra-rare overflow scan
            for (int i = 0; i < oc; ++i) {
                const int4 v = ovf[i];
                if (v.x == ng && active) {
                    const unsigned h = hidU[(size_t)v.y * 50 + lane];
                    const float wi = __int_as_float(v.z);
                    acc.x += wi * __uint_as_float(h << 16);
                    acc.y += wi * __uint_as_float(h & 0xFFFF0000u);
                }
            }
        }
        if (ng < N_NODES && active)
            *reinterpret_cast<float2*>(&out[(size_t)ng * DIM + 2 * lane]) = acc;
    }
}

// ---------------- fallback (atomic scatter, needs only 20MB ws) ----------
__global__ __launch_bounds__(256) void srgnn_gemm_bias(
    const float* __restrict__ x, const float* __restrict__ W,
    const float* __restrict__ b, float* __restrict__ hidden)
{
    __shared__ float Wt[DIM][DIM + 4];
    __shared__ float bs[DIM];
    __shared__ float xs[8][DIM];
    const int t = threadIdx.x;
    for (int i = t; i < DIM * DIM; i += 256) {
        int c = i / DIM, k = i - c * DIM;
        Wt[k][c] = W[i];
    }
    if (t < DIM) bs[t] = b[t];
    const int row0 = blockIdx.x * 8;
    for (int i = t; i < 8 * DIM; i += 256) {
        int r = i / DIM, k = i - r * DIM;
        int row = row0 + r;
        xs[r][k] = (row < N_NODES) ? x[row * DIM + k] : 0.0f;
    }
    __syncthreads();
    if (t < 200) {
        const int r  = t / 25;
        const int c4 = (t - r * 25) * 4;
        float acc0 = bs[c4 + 0], acc1 = bs[c4 + 1], acc2 = bs[c4 + 2], acc3 = bs[c4 + 3];
        for (int k = 0; k < DIM; ++k) {
            const float xv = xs[r][k];
            const float4 wv = *reinterpret_cast<const float4*>(&Wt[k][c4]);
            acc0 += xv * wv.x; acc1 += xv * wv.y; acc2 += xv * wv.z; acc3 += xv * wv.w;
        }
        const int row = row0 + r;
        if (row < N_NODES)
            *reinterpret_cast<float4*>(&hidden[row * DIM + c4]) =
                make_float4(acc0, acc1, acc2, acc3);
    }
}

__global__ __launch_bounds__(256) void srgnn_scatter_atomic(
    const float* __restrict__ hidden, const int* __restrict__ esrc,
    const int* __restrict__ edst, const float* __restrict__ ew,
    float* __restrict__ out)
{
    const unsigned gid = blockIdx.x * 256u + threadIdx.x;
    const unsigned e = gid / 25u;
    const unsigned j = gid - e * 25u;
    if (e >= N_EDGES) return;
    const int   s  = esrc[e];
    const int   d  = edst[e];
    const float wt = ew[e];
    const float4 h = *reinterpret_cast<const float4*>(&hidden[(size_t)s * DIM + j * 4]);
    float* op = &out[(size_t)d * DIM + j * 4];
    atomicAdd(op + 0, h.x * wt);
    atomicAdd(op + 1, h.y * wt);
    atomicAdd(op + 2, h.z * wt);
    atomicAdd(op + 3, h.w * wt);
}

extern "C" void kernel_launch(void* const* d_in, const int* in_sizes, int n_in,
                              void* d_out, int out_size, void* d_ws, size_t ws_size,
                              hipStream_t stream) {
    const float* x    = (const float*)d_in[0];
    const int*   esrc = (const int*)  d_in[1];
    const int*   edst = (const int*)  d_in[2];
    const float* ew   = (const float*)d_in[3];
    const float* W    = (const float*)d_in[4];
    const float* b    = (const float*)d_in[5];
    float* out = (float*)d_out;

    char* ws = (char*)d_ws;

    if (ws_size >= WS_NEED) {
        unsigned* hidU = (unsigned*)(ws + HIDB_OFF);
        int*      gcur = (int*)     (ws + GCUR_OFF);
        int*      ovfc = (int*)     (ws + OVFC_OFF);
        int4*     ovf  = (int4*)    (ws + OVF_OFF);
        uint2*    bkt2 = (uint2*)   (ws + BKT2_OFF);
        unsigned* WtU  = (unsigned*)(ws + WTU_OFF);

        // bf16 W^T build + zero control buffers (20 blocks cover 5000 thr)
        srgnn_transpose<<<(DIM * 50 + 255) / 256, 256, 0, stream>>>(
            W, WtU, gcur, ovfc);
        // fused: bin (196 blocks, FIRST) + byte-balanced GEMM (625 blocks)
        srgnn_gemm_bin<<<BIN_BLOCKS + GEMM_BLOCKS, 256, 0, stream>>>(
            x, WtU, b, hidU, esrc, edst, ew, gcur, ovfc, ovf, bkt2);
        // block-per-bucket LDS sort + aggregate
        srgnn_agg_s32<<<NB, 256, 0, stream>>>(hidU, gcur, bkt2, ovfc, ovf, out);
    } else {
        // fallback: atomic scatter
        float* hidden = (float*)ws;
        hipMemsetAsync(d_out, 0, (size_t)out_size * sizeof(float), stream);
        const int gemm_blocks = (N_NODES + 7) / 8;
        srgnn_gemm_bias<<<gemm_blocks, 256, 0, stream>>>(x, W, b, hidden);
        const long long work = (long long)N_EDGES * 25;
        const int scat_blocks = (int)((work + 255) / 256);
        srgnn_scatter_atomic<<<scat_blocks, 256, 0, stream>>>(hidden, esrc, edst, ew, out);
    }
}

// Round 21
// 67.938 us; speedup vs baseline: 1.6224x; 1.0365x over previous
//
#include <hip/hip_runtime.h>

#define N_NODES 50000
#define N_EDGES 800000
#define DIM 100

#define NB      1563        // buckets of 32 nodes: ceil(50000/32)
#define CAPB    768         // records per bucket region (mean 512, +11 sigma)
#define OVF_CAP 4096
#define EPB     4096        // edges per bin block
#define BIN_BLOCKS  196     // ceil(800000 / 4096)
#define GEMM_BLOCKS 782     // ceil(3125 row-tiles / 4 waves)
#define N_ROWTILES 3125     // 50000 / 16

// ---------------- workspace layout (bytes) ----------------
#define HIDB_OFF  0u            // bf16 hidden, ushort[50000*100]       10,000,000
#define GCUR_OFF  10000000u     // int gcur[1563]                            6,256
#define OVFC_OFF  10006256u     // int ovf_cnt (+pad)                           16
#define OVF_OFF   10006272u     // int4 ovf[4096]                           65,536
#define BKT2_OFF  10071808u     // uint2 bkt2[1563*768] (128B-aligned)   9,603,072
#define WS_NEED   19674880u

typedef __attribute__((ext_vector_type(8))) short short8;
typedef __attribute__((ext_vector_type(4))) float f32x4;
union frag { unsigned u[4]; short8 s; };

// float->bf16 RNE helpers
__device__ inline unsigned bf16hi(float v) {            // bf16 in HIGH 16 bits
    unsigned u = __float_as_uint(v);
    u += 0x7FFFu + ((u >> 16) & 1u);
    return u & 0xFFFF0000u;
}
__device__ inline unsigned bf16pair(float lo, float hi) {  // lo in LOW ushort
    unsigned ulo = __float_as_uint(lo); ulo += 0x7FFFu + ((ulo >> 16) & 1u);
    unsigned uhi = __float_as_uint(hi); uhi += 0x7FFFu + ((uhi >> 16) & 1u);
    return (ulo >> 16) | (uhi & 0xFFFF0000u);
}

// ---------------- fused bin + MFMA GEMM (bin FIRST: bid<196) --------------
// bin role: single-pass bucket scatter, 4096 edges/block (R20, measured).
// gemm role: hidden(bf16) = x @ W^T + b via mfma_f32_16x16x32_bf16.
// One wave per 16-row tile; A = x rows (lane&15 = row, 8 k/lane), B = W
// rows directly (lane&15 = out col; Wt[k][c] = W[c][k] -> no transpose
// needed). K=100 padded to 128 with zero fragments. 7 col-tiles reuse the
// A fragments so x is read once. C/D: col=lane&15, row=(lane>>4)*4+reg
// (verified m89 mapping). f32 accumulate + f32 bias -> RNE bf16 store.
__global__ __launch_bounds__(256) void srgnn_gemm_bin(
    const float* __restrict__ x, const float* __restrict__ W,
    const float* __restrict__ b, unsigned short* __restrict__ hid16,
    const int* __restrict__ esrc, const int* __restrict__ edst,
    const float* __restrict__ ew, int* __restrict__ gcur,
    int* __restrict__ ovfc, int4* __restrict__ ovf, uint2* __restrict__ bkt2)
{
    __shared__ __align__(16) char smem[12544];
    const int t = threadIdx.x;

    if (blockIdx.x < BIN_BLOCKS) {
        // ---------------- bin part ----------------
        int* hist = (int*)smem;                      // NB ints
        int* lcur = hist + NB;                       // NB ints (12504 B)
        const int e0 = blockIdx.x * EPB;

        for (int i = t; i < NB; i += 256) hist[i] = 0;
        __syncthreads();

        int d[16];
        #pragma unroll
        for (int k = 0; k < 16; ++k) {
            const int e = e0 + t + k * 256;
            d[k] = (e < N_EDGES) ? edst[e] : -1;
            if (d[k] >= 0) atomicAdd(&hist[d[k] >> 5], 1);
        }
        __syncthreads();
        for (int i = t; i < NB; i += 256)
            if (hist[i]) lcur[i] = atomicAdd(&gcur[i], hist[i]);
        __syncthreads();
        #pragma unroll
        for (int k = 0; k < 16; ++k) {
            if (d[k] >= 0) {
                const int e = e0 + t + k * 256;
                const int s = esrc[e];
                const float w = ew[e];
                const int bq = d[k] >> 5;
                const int pos = atomicAdd(&lcur[bq], 1);
                if (pos < CAPB) {
                    bkt2[(size_t)bq * CAPB + pos] =
                        make_uint2((unsigned)s | bf16hi(w), (unsigned)d[k]);
                } else {
                    const int op = atomicAdd(ovfc, 1);
                    if (op < OVF_CAP) ovf[op] = make_int4(d[k], s, __float_as_int(w), 0);
                }
            }
        }
    } else {
        // ---------------- MFMA GEMM part ----------------
        const int gb = blockIdx.x - BIN_BLOCKS;
        const int wv = gb * 4 + (t >> 6);            // row-tile id
        if (wv >= N_ROWTILES) return;
        const int l   = t & 63;
        const int r16 = l & 15;
        const int kg  = l >> 4;                      // k-group 0..3
        const int row = wv * 16 + r16;               // A row (always < 50000)

        // A fragments: x[row][kt*32 + kg*8 .. +7], K padded 100->128
        frag A[4];
        #pragma unroll
        for (int kt = 0; kt < 4; ++kt) {
            float4 fa = make_float4(0.f, 0.f, 0.f, 0.f);
            float4 fb = make_float4(0.f, 0.f, 0.f, 0.f);
            if (kt < 3) {
                const float* px = &x[(size_t)row * DIM + kt * 32 + kg * 8];
                fa = *reinterpret_cast<const float4*>(px);
                fb = *reinterpret_cast<const float4*>(px + 4);
            } else if (kg == 0) {                    // k = 96..99 (+ zeros)
                fa = *reinterpret_cast<const float4*>(&x[(size_t)row * DIM + 96]);
            }
            A[kt].u[0] = bf16pair(fa.x, fa.y);
            A[kt].u[1] = bf16pair(fa.z, fa.w);
            A[kt].u[2] = bf16pair(fb.x, fb.y);
            A[kt].u[3] = bf16pair(fb.z, fb.w);
        }

        for (int ct = 0; ct < 7; ++ct) {             // 7 col tiles (last masked)
            const int col = ct * 16 + r16;
            const bool cok = (col < DIM);
            frag B[4];
            #pragma unroll
            for (int kt = 0; kt < 4; ++kt) {
                float4 fa = make_float4(0.f, 0.f, 0.f, 0.f);
                float4 fb = make_float4(0.f, 0.f, 0.f, 0.f);
                if (cok) {                           // B[k][col] = W[col][k]
                    if (kt < 3) {
                        const float* pw = &W[(size_t)col * DIM + kt * 32 + kg * 8];
                        fa = *reinterpret_cast<const float4*>(pw);
                        fb = *reinterpret_cast<const float4*>(pw + 4);
                    } else if (kg == 0) {
                        fa = *reinterpret_cast<const float4*>(&W[(size_t)col * DIM + 96]);
                    }
                }
                B[kt].u[0] = bf16pair(fa.x, fa.y);
                B[kt].u[1] = bf16pair(fa.z, fa.w);
                B[kt].u[2] = bf16pair(fb.x, fb.y);
                B[kt].u[3] = bf16pair(fb.z, fb.w);
            }
            f32x4 acc = {0.f, 0.f, 0.f, 0.f};
            #pragma unroll
            for (int kt = 0; kt < 4; ++kt)
                acc = __builtin_amdgcn_mfma_f32_16x16x32_bf16(
                    A[kt].s, B[kt].s, acc, 0, 0, 0);

            if (cok) {
                const float bc = b[col];
                #pragma unroll
                for (int reg = 0; reg < 4; ++reg) {
                    const int orow = wv * 16 + kg * 4 + reg;   // C/D row map
                    float v = acc[reg] + bc;
                    unsigned uu = __float_as_uint(v);
                    uu += 0x7FFFu + ((uu >> 16) & 1u);
                    hid16[(size_t)orow * DIM + col] = (unsigned short)(uu >> 16);
                }
            }
        }
    }
}

// ---------------- aggregate: block per 32-node bucket, LDS counting sort --
__global__ __launch_bounds__(256) void srgnn_agg_s32(
    const unsigned* __restrict__ hidU, const int* __restrict__ gcur,
    const uint2* __restrict__ bkt2, const int* __restrict__ ovfc,
    const int4* __restrict__ ovf, float* __restrict__ out)
{
    __shared__ uint2    recs[CAPB];     // 6144 B
    __shared__ unsigned srt[CAPB];      // 3072 B
    __shared__ int nh[32], sc[32], cur[32];

    const int t = threadIdx.x;
    const int bq = blockIdx.x;
    int cntb = gcur[bq];
    if (cntb > CAPB) cntb = CAPB;

    if (t < 32) nh[t] = 0;
    __syncthreads();
    for (int i = t; i < cntb; i += 256) {
        const uint2 r = bkt2[(size_t)bq * CAPB + i];
        recs[i] = r;
        atomicAdd(&nh[r.y & 31], 1);
    }
    __syncthreads();
    if (t < 32) sc[t] = nh[t];
    __syncthreads();
    for (int ofs = 1; ofs < 32; ofs <<= 1) {         // Hillis-Steele inclusive
        int a = 0;
        if (t < 32 && t >= ofs) a = sc[t - ofs];
        __syncthreads();
        if (t < 32) sc[t] += a;
        __syncthreads();
    }
    if (t < 32) cur[t] = sc[t] - nh[t];
    __syncthreads();
    for (int i = t; i < cntb; i += 256) {
        const uint2 r = recs[i];
        const int pos = atomicAdd(&cur[r.y & 31], 1);
        srt[pos] = r.x;                              // src | bf16(w)<<16
    }
    __syncthreads();

    int oc = *ovfc;                                  // ~always 0
    if (oc > OVF_CAP) oc = OVF_CAP;
    const int lane = t & 63;
    const int wid  = t >> 6;                         // 4 waves
    const bool active = (lane < 50);

    for (int q = 0; q < 8; ++q) {
        const int n  = wid * 8 + q;                  // 4 waves x 8 = 32 nodes
        const int s1 = sc[n];
        const int s0 = s1 - nh[n];
        float2 acc = make_float2(0.f, 0.f);

        int p = s0;
        for (; p + 8 <= s1; p += 8) {                // 8-deep MLP
            unsigned r[8], h[8];
            #pragma unroll
            for (int j = 0; j < 8; ++j) r[j] = srt[p + j];
            if (active) {
                #pragma unroll
                for (int j = 0; j < 8; ++j)
                    h[j] = hidU[(size_t)(r[j] & 0xFFFFu) * 50 + lane];
                #pragma unroll
                for (int j = 0; j < 8; ++j) {
                    const float wj = __uint_as_float(r[j] & 0xFFFF0000u);
                    acc.x += wj * __uint_as_float(h[j] << 16);
                    acc.y += wj * __uint_as_float(h[j] & 0xFFFF0000u);
                }
            }
        }
        for (; p < s1; ++p) {
            const unsigned r = srt[p];
            const float wi = __uint_as_float(r & 0xFFFF0000u);
            if (active) {
                const unsigned h = hidU[(size_t)(r & 0xFFFFu) * 50 + lane];
                acc.x += wi * __uint_as_float(h << 16);
                acc.y += wi * __uint_as_float(h & 0xFFFF0000u);
            }
        }

        const int ng = bq * 32 + n;
        if (oc > 0) {                                // ultra-rare overflow scan
            for (int i = 0; i < oc; ++i) {
                const int4 v = ovf[i];
                if (v.x == ng && active) {
                    const unsigned h = hidU[(size_t)v.y * 50 + lane];
                    const float wi = __int_as_float(v.z);
                    acc.x += wi * __uint_as_float(h << 16);
                    acc.y += wi * __uint_as_float(h & 0xFFFF0000u);
                }
            }
        }
        if (ng < N_NODES && active)
            *reinterpret_cast<float2*>(&out[(size_t)ng * DIM + 2 * lane]) = acc;
    }
}

// ---------------- fallback (atomic scatter, needs only 20MB ws) ----------
__global__ __launch_bounds__(256) void srgnn_gemm_bias(
    const float* __restrict__ x, const float* __restrict__ W,
    const float* __restrict__ b, float* __restrict__ hidden)
{
    __shared__ float Wt[DIM][DIM + 4];
    __shared__ float bs[DIM];
    __shared__ float xs[8][DIM];
    const int t = threadIdx.x;
    for (int i = t; i < DIM * DIM; i += 256) {
        int c = i / DIM, k = i - c * DIM;
        Wt[k][c] = W[i];
    }
    if (t < DIM) bs[t] = b[t];
    const int row0 = blockIdx.x * 8;
    for (int i = t; i < 8 * DIM; i += 256) {
        int r = i / DIM, k = i - r * DIM;
        int row = row0 + r;
        xs[r][k] = (row < N_NODES) ? x[row * DIM + k] : 0.0f;
    }
    __syncthreads();
    if (t < 200) {
        const int r  = t / 25;
        const int c4 = (t - r * 25) * 4;
        float acc0 = bs[c4 + 0], acc1 = bs[c4 + 1], acc2 = bs[c4 + 2], acc3 = bs[c4 + 3];
        for (int k = 0; k < DIM; ++k) {
            const float xv = xs[r][k];
            const float4 wv = *reinterpret_cast<const float4*>(&Wt[k][c4]);
            acc0 += xv * wv.x; acc1 += xv * wv.y; acc2 += xv * wv.z; acc3 += xv * wv.w;
        }
        const int row = row0 + r;
        if (row < N_NODES)
            *reinterpret_cast<float4*>(&hidden[row * DIM + c4]) =
                make_float4(acc0, acc1, acc2, acc3);
    }
}

__global__ __launch_bounds__(256) void srgnn_scatter_atomic(
    const float* __restrict__ hidden, const int* __restrict__ esrc,
    const int* __restrict__ edst, const float* __restrict__ ew,
    float* __restrict__ out)
{
    const unsigned gid = blockIdx.x * 256u + threadIdx.x;
    const unsigned e = gid / 25u;
    const unsigned j = gid - e * 25u;
    if (e >= N_EDGES) return;
    const int   s  = esrc[e];
    const int   d  = edst[e];
    const float wt = ew[e];
    const float4 h = *reinterpret_cast<const float4*>(&hidden[(size_t)s * DIM + j * 4]);
    float* op = &out[(size_t)d * DIM + j * 4];
    atomicAdd(op + 0, h.x * wt);
    atomicAdd(op + 1, h.y * wt);
    atomicAdd(op + 2, h.z * wt);
    atomicAdd(op + 3, h.w * wt);
}

extern "C" void kernel_launch(void* const* d_in, const int* in_sizes, int n_in,
                              void* d_out, int out_size, void* d_ws, size_t ws_size,
                              hipStream_t stream) {
    const float* x    = (const float*)d_in[0];
    const int*   esrc = (const int*)  d_in[1];
    const int*   edst = (const int*)  d_in[2];
    const float* ew   = (const float*)d_in[3];
    const float* W    = (const float*)d_in[4];
    const float* b    = (const float*)d_in[5];
    float* out = (float*)d_out;

    char* ws = (char*)d_ws;

    if (ws_size >= WS_NEED) {
        unsigned short* hid16 = (unsigned short*)(ws + HIDB_OFF);
        unsigned* hidU = (unsigned*)(ws + HIDB_OFF);
        int*      gcur = (int*)     (ws + GCUR_OFF);
        int4*     ovf  = (int4*)    (ws + OVF_OFF);
        int*      ovfc = (int*)     (ws + OVFC_OFF);
        uint2*    bkt2 = (uint2*)   (ws + BKT2_OFF);

        // zero bucket cursors + overflow counter (contiguous region)
        hipMemsetAsync(gcur, 0, (OVFC_OFF - GCUR_OFF) + 16, stream);
        // fused: bin (196 blocks, FIRST) + MFMA GEMM (782 blocks)
        srgnn_gemm_bin<<<BIN_BLOCKS + GEMM_BLOCKS, 256, 0, stream>>>(
            x, W, b, hid16, esrc, edst, ew, gcur, ovfc, ovf, bkt2);
        // block-per-bucket LDS sort + aggregate
        srgnn_agg_s32<<<NB, 256, 0, stream>>>(hidU, gcur, bkt2, ovfc, ovf, out);
    } else {
        // fallback: atomic scatter
        float* hidden = (float*)ws;
        hipMemsetAsync(d_out, 0, (size_t)out_size * sizeof(float), stream);
        const int gemm_blocks = (N_NODES + 7) / 8;
        srgnn_gemm_bias<<<gemm_blocks, 256, 0, stream>>>(x, W, b, hidden);
        const long long work = (long long)N_EDGES * 25;
        const int scat_blocks = (int)((work + 255) / 256);
        srgnn_scatter_atomic<<<scat_blocks, 256, 0, stream>>>(hidden, esrc, edst, ew, out);
    }
}

// Round 22
// 67.450 us; speedup vs baseline: 1.6341x; 1.0072x over previous
//
#include <hip/hip_runtime.h>

#define N_NODES 50000
#define N_EDGES 800000
#define DIM 100

#define NB      782         // buckets of 64 nodes: ceil(50000/64)
#define CAPB    1280        // records per bucket region (mean 1024, +8 sigma)
#define OVF_CAP 4096
#define EPB     4096        // edges per bin block
#define BIN_BLOCKS  196     // ceil(800000 / 4096)
#define GEMM_BLOCKS 782     // ceil(3125 row-tiles / 4 waves)
#define N_ROWTILES 3125     // 50000 / 16

// ---------------- workspace layout (bytes) ----------------
#define HIDB_OFF  0u            // bf16 hidden, ushort[50000*100]       10,000,000
#define GCUR_OFF  10000000u     // int gcur[782]                             3,128
#define OVFC_OFF  10003128u     // int ovf_cnt (+pad)                           24
#define OVF_OFF   10003152u     // int4 ovf[4096]                           65,536
#define BKT2_OFF  10068736u     // uint2 bkt2[782*1280] (128B-aligned)   8,007,680
#define WS_NEED   18076416u

typedef __attribute__((ext_vector_type(8))) short short8;
typedef __attribute__((ext_vector_type(4))) float f32x4;
union frag { unsigned u[4]; short8 s; };

// float->bf16 RNE helpers
__device__ inline unsigned bf16hi(float v) {            // bf16 in HIGH 16 bits
    unsigned u = __float_as_uint(v);
    u += 0x7FFFu + ((u >> 16) & 1u);
    return u & 0xFFFF0000u;
}
__device__ inline unsigned bf16pair(float lo, float hi) {  // lo in LOW ushort
    unsigned ulo = __float_as_uint(lo); ulo += 0x7FFFu + ((ulo >> 16) & 1u);
    unsigned uhi = __float_as_uint(hi); uhi += 0x7FFFu + ((uhi >> 16) & 1u);
    return (ulo >> 16) | (uhi & 0xFFFF0000u);
}

// ---------------- fused bin + MFMA GEMM (bin FIRST: bid<196) --------------
// bin role: single-pass bucket scatter into 782 64-node buckets (runs of
// ~5.2 records = 42B -> ~1 line writeback per run instead of 2.6-record
// runs at 1563 buckets).
// gemm role: hidden(bf16) = x @ W^T + b via mfma_f32_16x16x32_bf16 (R21,
// verified absmax 0.0625). B = W rows directly (no transpose); K padded
// 100->128; 7 col-tiles reuse A fragments; C/D map col=lane&15,
// row=(lane>>4)*4+reg.
__global__ __launch_bounds__(256) void srgnn_gemm_bin(
    const float* __restrict__ x, const float* __restrict__ W,
    const float* __restrict__ b, unsigned short* __restrict__ hid16,
    const int* __restrict__ esrc, const int* __restrict__ edst,
    const float* __restrict__ ew, int* __restrict__ gcur,
    int* __restrict__ ovfc, int4* __restrict__ ovf, uint2* __restrict__ bkt2)
{
    __shared__ __align__(16) char smem[6272];
    const int t = threadIdx.x;

    if (blockIdx.x < BIN_BLOCKS) {
        // ---------------- bin part ----------------
        int* hist = (int*)smem;                      // NB ints
        int* lcur = hist + NB;                       // NB ints (6256 B)
        const int e0 = blockIdx.x * EPB;

        for (int i = t; i < NB; i += 256) hist[i] = 0;
        __syncthreads();

        int d[16];
        #pragma unroll
        for (int k = 0; k < 16; ++k) {
            const int e = e0 + t + k * 256;
            d[k] = (e < N_EDGES) ? edst[e] : -1;
            if (d[k] >= 0) atomicAdd(&hist[d[k] >> 6], 1);
        }
        __syncthreads();
        for (int i = t; i < NB; i += 256)
            if (hist[i]) lcur[i] = atomicAdd(&gcur[i], hist[i]);
        __syncthreads();
        #pragma unroll
        for (int k = 0; k < 16; ++k) {
            if (d[k] >= 0) {
                const int e = e0 + t + k * 256;
                const int s = esrc[e];
                const float w = ew[e];
                const int bq = d[k] >> 6;
                const int pos = atomicAdd(&lcur[bq], 1);
                if (pos < CAPB) {
                    bkt2[(size_t)bq * CAPB + pos] =
                        make_uint2((unsigned)s | bf16hi(w), (unsigned)d[k]);
                } else {
                    const int op = atomicAdd(ovfc, 1);
                    if (op < OVF_CAP) ovf[op] = make_int4(d[k], s, __float_as_int(w), 0);
                }
            }
        }
    } else {
        // ---------------- MFMA GEMM part ----------------
        const int gb = blockIdx.x - BIN_BLOCKS;
        const int wv = gb * 4 + (t >> 6);            // row-tile id
        if (wv >= N_ROWTILES) return;
        const int l   = t & 63;
        const int r16 = l & 15;
        const int kg  = l >> 4;                      // k-group 0..3
        const int row = wv * 16 + r16;               // A row (always < 50000)

        // A fragments: x[row][kt*32 + kg*8 .. +7], K padded 100->128
        frag A[4];
        #pragma unroll
        for (int kt = 0; kt < 4; ++kt) {
            float4 fa = make_float4(0.f, 0.f, 0.f, 0.f);
            float4 fb = make_float4(0.f, 0.f, 0.f, 0.f);
            if (kt < 3) {
                const float* px = &x[(size_t)row * DIM + kt * 32 + kg * 8];
                fa = *reinterpret_cast<const float4*>(px);
                fb = *reinterpret_cast<const float4*>(px + 4);
            } else if (kg == 0) {                    // k = 96..99 (+ zeros)
                fa = *reinterpret_cast<const float4*>(&x[(size_t)row * DIM + 96]);
            }
            A[kt].u[0] = bf16pair(fa.x, fa.y);
            A[kt].u[1] = bf16pair(fa.z, fa.w);
            A[kt].u[2] = bf16pair(fb.x, fb.y);
            A[kt].u[3] = bf16pair(fb.z, fb.w);
        }

        for (int ct = 0; ct < 7; ++ct) {             // 7 col tiles (last masked)
            const int col = ct * 16 + r16;
            const bool cok = (col < DIM);
            frag B[4];
            #pragma unroll
            for (int kt = 0; kt < 4; ++kt) {
                float4 fa = make_float4(0.f, 0.f, 0.f, 0.f);
                float4 fb = make_float4(0.f, 0.f, 0.f, 0.f);
                if (cok) {                           // B[k][col] = W[col][k]
                    if (kt < 3) {
                        const float* pw = &W[(size_t)col * DIM + kt * 32 + kg * 8];
                        fa = *reinterpret_cast<const float4*>(pw);
                        fb = *reinterpret_cast<const float4*>(pw + 4);
                    } else if (kg == 0) {
                        fa = *reinterpret_cast<const float4*>(&W[(size_t)col * DIM + 96]);
                    }
                }
                B[kt].u[0] = bf16pair(fa.x, fa.y);
                B[kt].u[1] = bf16pair(fa.z, fa.w);
                B[kt].u[2] = bf16pair(fb.x, fb.y);
                B[kt].u[3] = bf16pair(fb.z, fb.w);
            }
            f32x4 acc = {0.f, 0.f, 0.f, 0.f};
            #pragma unroll
            for (int kt = 0; kt < 4; ++kt)
                acc = __builtin_amdgcn_mfma_f32_16x16x32_bf16(
                    A[kt].s, B[kt].s, acc, 0, 0, 0);

            if (cok) {
                const float bc = b[col];
                #pragma unroll
                for (int reg = 0; reg < 4; ++reg) {
                    const int orow = wv * 16 + kg * 4 + reg;   // C/D row map
                    float v = acc[reg] + bc;
                    unsigned uu = __float_as_uint(v);
                    uu += 0x7FFFu + ((uu >> 16) & 1u);
                    hid16[(size_t)orow * DIM + col] = (unsigned short)(uu >> 16);
                }
            }
        }
    }
}

// ---------------- aggregate: block per 64-node bucket, LDS counting sort --
// 512 thr / 8 waves, ~16.4KB LDS. Stage ~1024 records coalesced, LDS
// counting-sort by node, then wave-per-node x8: LDS broadcast records,
// bf16 row gathers 8-deep, f32 register accumulate, plain float2 store.
__global__ __launch_bounds__(512) void srgnn_agg_s64(
    const unsigned* __restrict__ hidU, const int* __restrict__ gcur,
    const uint2* __restrict__ bkt2, const int* __restrict__ ovfc,
    const int4* __restrict__ ovf, float* __restrict__ out)
{
    __shared__ uint2    recs[CAPB];     // 10240 B
    __shared__ unsigned srt[CAPB];      //  5120 B
    __shared__ int nh[64], sc[64], cur[64];

    const int t = threadIdx.x;
    const int bq = blockIdx.x;
    int cntb = gcur[bq];
    if (cntb > CAPB) cntb = CAPB;

    if (t < 64) nh[t] = 0;
    __syncthreads();
    for (int i = t; i < cntb; i += 512) {
        const uint2 r = bkt2[(size_t)bq * CAPB + i];
        recs[i] = r;
        atomicAdd(&nh[r.y & 63], 1);
    }
    __syncthreads();
    if (t < 64) sc[t] = nh[t];
    __syncthreads();
    for (int ofs = 1; ofs < 64; ofs <<= 1) {         // Hillis-Steele inclusive
        int a = 0;
        if (t < 64 && t >= ofs) a = sc[t - ofs];
        __syncthreads();
        if (t < 64) sc[t] += a;
        __syncthreads();
    }
    if (t < 64) cur[t] = sc[t] - nh[t];
    __syncthreads();
    for (int i = t; i < cntb; i += 512) {
        const uint2 r = recs[i];
        const int pos = atomicAdd(&cur[r.y & 63], 1);
        srt[pos] = r.x;                              // src | bf16(w)<<16
    }
    __syncthreads();

    int oc = *ovfc;                                  // ~always 0
    if (oc > OVF_CAP) oc = OVF_CAP;
    const int lane = t & 63;
    const int wid  = t >> 6;                         // 8 waves
    const bool active = (lane < 50);

    for (int q = 0; q < 8; ++q) {
        const int n  = wid * 8 + q;                  // 8 waves x 8 = 64 nodes
        const int s1 = sc[n];
        const int s0 = s1 - nh[n];
        float2 acc = make_float2(0.f, 0.f);

        int p = s0;
        for (; p + 8 <= s1; p += 8) {                // 8-deep MLP
            unsigned r[8], h[8];
            #pragma unroll
            for (int j = 0; j < 8; ++j) r[j] = srt[p + j];
            if (active) {
                #pragma unroll
                for (int j = 0; j < 8; ++j)
                    h[j] = hidU[(size_t)(r[j] & 0xFFFFu) * 50 + lane];
                #pragma unroll
                for (int j = 0; j < 8; ++j) {
                    const float wj = __uint_as_float(r[j] & 0xFFFF0000u);
                    acc.x += wj * __uint_as_float(h[j] << 16);
                    acc.y += wj * __uint_as_float(h[j] & 0xFFFF0000u);
                }
            }
        }
        for (; p < s1; ++p) {
            const unsigned r = srt[p];
            const float wi = __uint_as_float(r & 0xFFFF0000u);
            if (active) {
                const unsigned h = hidU[(size_t)(r & 0xFFFFu) * 50 + lane];
                acc.x += wi * __uint_as_float(h << 16);
                acc.y += wi * __uint_as_float(h & 0xFFFF0000u);
            }
        }

        const int ng = bq * 64 + n;
        if (oc > 0) {                                // ultra-rare overflow scan
            for (int i = 0; i < oc; ++i) {
                const int4 v = ovf[i];
                if (v.x == ng && active) {
                    const unsigned h = hidU[(size_t)v.y * 50 + lane];
                    const float wi = __int_as_float(v.z);
                    acc.x += wi * __uint_as_float(h << 16);
                    acc.y += wi * __uint_as_float(h & 0xFFFF0000u);
                }
            }
        }
        if (ng < N_NODES && active)
            *reinterpret_cast<float2*>(&out[(size_t)ng * DIM + 2 * lane]) = acc;
    }
}

// ---------------- fallback (atomic scatter, needs only 20MB ws) ----------
__global__ __launch_bounds__(256) void srgnn_gemm_bias(
    const float* __restrict__ x, const float* __restrict__ W,
    const float* __restrict__ b, float* __restrict__ hidden)
{
    __shared__ float Wt[DIM][DIM + 4];
    __shared__ float bs[DIM];
    __shared__ float xs[8][DIM];
    const int t = threadIdx.x;
    for (int i = t; i < DIM * DIM; i += 256) {
        int c = i / DIM, k = i - c * DIM;
        Wt[k][c] = W[i];
    }
    if (t < DIM) bs[t] = b[t];
    const int row0 = blockIdx.x * 8;
    for (int i = t; i < 8 * DIM; i += 256) {
        int r = i / DIM, k = i - r * DIM;
        int row = row0 + r;
        xs[r][k] = (row < N_NODES) ? x[row * DIM + k] : 0.0f;
    }
    __syncthreads();
    if (t < 200) {
        const int r  = t / 25;
        const int c4 = (t - r * 25) * 4;
        float acc0 = bs[c4 + 0], acc1 = bs[c4 + 1], acc2 = bs[c4 + 2], acc3 = bs[c4 + 3];
        for (int k = 0; k < DIM; ++k) {
            const float xv = xs[r][k];
            const float4 wv = *reinterpret_cast<const float4*>(&Wt[k][c4]);
            acc0 += xv * wv.x; acc1 += xv * wv.y; acc2 += xv * wv.z; acc3 += xv * wv.w;
        }
        const int row = row0 + r;
        if (row < N_NODES)
            *reinterpret_cast<float4*>(&hidden[row * DIM + c4]) =
                make_float4(acc0, acc1, acc2, acc3);
    }
}

__global__ __launch_bounds__(256) void srgnn_scatter_atomic(
    const float* __restrict__ hidden, const int* __restrict__ esrc,
    const int* __restrict__ edst, const float* __restrict__ ew,
    float* __restrict__ out)
{
    const unsigned gid = blockIdx.x * 256u + threadIdx.x;
    const unsigned e = gid / 25u;
    const unsigned j = gid - e * 25u;
    if (e >= N_EDGES) return;
    const int   s  = esrc[e];
    const int   d  = edst[e];
    const float wt = ew[e];
    const float4 h = *reinterpret_cast<const float4*>(&hidden[(size_t)s * DIM + j * 4]);
    float* op = &out[(size_t)d * DIM + j * 4];
    atomicAdd(op + 0, h.x * wt);
    atomicAdd(op + 1, h.y * wt);
    atomicAdd(op + 2, h.z * wt);
    atomicAdd(op + 3, h.w * wt);
}

extern "C" void kernel_launch(void* const* d_in, const int* in_sizes, int n_in,
                              void* d_out, int out_size, void* d_ws, size_t ws_size,
                              hipStream_t stream) {
    const float* x    = (const float*)d_in[0];
    const int*   esrc = (const int*)  d_in[1];
    const int*   edst = (const int*)  d_in[2];
    const float* ew   = (const float*)d_in[3];
    const float* W    = (const float*)d_in[4];
    const float* b    = (const float*)d_in[5];
    float* out = (float*)d_out;

    char* ws = (char*)d_ws;

    if (ws_size >= WS_NEED) {
        unsigned short* hid16 = (unsigned short*)(ws + HIDB_OFF);
        unsigned* hidU = (unsigned*)(ws + HIDB_OFF);
        int*      gcur = (int*)     (ws + GCUR_OFF);
        int*      ovfc = (int*)     (ws + OVFC_OFF);
        int4*     ovf  = (int4*)    (ws + OVF_OFF);
        uint2*    bkt2 = (uint2*)   (ws + BKT2_OFF);

        // zero bucket cursors + overflow counter (contiguous region)
        hipMemsetAsync(gcur, 0, (OVFC_OFF - GCUR_OFF) + 24, stream);
        // fused: bin (196 blocks, FIRST) + MFMA GEMM (782 blocks)
        srgnn_gemm_bin<<<BIN_BLOCKS + GEMM_BLOCKS, 256, 0, stream>>>(
            x, W, b, hid16, esrc, edst, ew, gcur, ovfc, ovf, bkt2);
        // block-per-64-node-bucket LDS sort + aggregate
        srgnn_agg_s64<<<NB, 512, 0, stream>>>(hidU, gcur, bkt2, ovfc, ovf, out);
    } else {
        // fallback: atomic scatter
        float* hidden = (float*)ws;
        hipMemsetAsync(d_out, 0, (size_t)out_size * sizeof(float), stream);
        const int gemm_blocks = (N_NODES + 7) / 8;
        srgnn_gemm_bias<<<gemm_blocks, 256, 0, stream>>>(x, W, b, hidden);
        const long long work = (long long)N_EDGES * 25;
        const int scat_blocks = (int)((work + 255) / 256);
        srgnn_scatter_atomic<<<scat_blocks, 256, 0, stream>>>(hidden, esrc, edst, ew, out);
    }
}